// Round 3
// baseline (208.136 us; speedup 1.0000x reference)
//
#include <hip/hip_runtime.h>
#include <cstdint>

#define BLOCK 512
#define NWAVES 8
#define B_SZ 512
#define N_SZ 8732
#define NG (N_SZ/4)   // 2183, N divisible by 4

__device__ __forceinline__ float f4c(const float4& v, int j) {
  return j==0 ? v.x : (j==1 ? v.y : (j==2 ? v.z : v.w));
}
__device__ __forceinline__ int i4c(const int4& v, int j) {
  return j==0 ? v.x : (j==1 ? v.y : (j==2 ? v.z : v.w));
}
__device__ __forceinline__ float smoothl1(float d) {
  float ad = fabsf(d);
  return ad < 1.0f ? 0.5f*d*d : ad - 0.5f;
}

// One block per batch row. Computes loc_loss, closs, mask stats; stores
// con_neg (as uint bits, all >= 0) in LDS; exact top-K via 4-pass radix
// select; writes per-row (total / pos) or 0 to rowout[b].
__global__ __launch_bounds__(BLOCK, 4)
void mbl_row_kernel(const float* __restrict__ ploc,
                    const float* __restrict__ pconf,
                    const float* __restrict__ gloc,
                    const int*   __restrict__ glabel,
                    const float* __restrict__ dboxes,
                    float* __restrict__ rowout)
{
  __shared__ __align__(16) uint32_t con[N_SZ];  // 34928 B: whole row's con_neg bits
  __shared__ uint32_t hist[NWAVES*256];         // per-wave histograms, 8 KB
  __shared__ uint32_t scan[256];
  __shared__ float redf[NWAVES], redf2[NWAVES];
  __shared__ int   redi[NWAVES];
  __shared__ int sh_pos, sh_rem;
  __shared__ uint32_t sh_prefix;
  __shared__ float sh_loc, sh_pcl;

  const int b   = blockIdx.x;
  const int tid = threadIdx.x;
  const int wid = tid >> 6;
  const int lane = tid & 63;

  const float* pl  = ploc  + (size_t)b * (4*N_SZ);
  const float* pc  = pconf + (size_t)b * (2*N_SZ);
  const float4* gl4  = (const float4*)(gloc   + (size_t)b * (N_SZ*4));
  const int4*   lab4 = (const int4*)  (glabel + (size_t)b * N_SZ);
  const float4* db4  = (const float4*)dboxes;

  float loc_acc = 0.f, pcl_acc = 0.f;
  int pos_acc = 0;

  // ---- Phase A: streaming compute (HBM-bound part) ----
  for (int g = tid; g < NG; g += BLOCK) {
    const int n = g*4;
    float4 pl0 = *(const float4*)(pl + n);
    float4 pl1 = *(const float4*)(pl + N_SZ   + n);
    float4 pl2 = *(const float4*)(pl + 2*N_SZ + n);
    float4 pl3 = *(const float4*)(pl + 3*N_SZ + n);
    float4 pc0 = *(const float4*)(pc + n);
    float4 pc1 = *(const float4*)(pc + N_SZ + n);
    int4 lb = lab4[g];
    uint32_t cw[4];
    #pragma unroll
    for (int j = 0; j < 4; ++j) {
      float4 g4 = gl4[n + j];
      float4 d4 = db4[n + j];
      float dxy0 = d4.x - 0.5f*d4.z;
      float dxy1 = d4.y - 0.5f*d4.w;
      float dwh0 = d4.x + 0.5f*d4.z;
      float dwh1 = d4.y + 0.5f*d4.w;
      float go0 = (g4.x - dxy0) / dwh0;
      float go1 = (g4.y - dxy1) / dwh1;
      float go2 = logf(g4.z / dwh0);
      float go3 = logf(g4.w / dwh1);
      float s = smoothl1(f4c(pl0,j) - go0)
              + smoothl1(f4c(pl1,j) - go1)
              + smoothl1(f4c(pl2,j) - go2)
              + smoothl1(f4c(pl3,j) - go3);
      float x0 = f4c(pc0,j), x1 = f4c(pc1,j);
      float mx  = fmaxf(x0, x1);
      float lse = mx + logf(expf(x0-mx) + expf(x1-mx));
      int L = i4c(lb, j);
      float closs = lse - (L ? x1 : x0);   // >= 0 always
      if (L > 0) {
        pos_acc += 1;
        loc_acc += s;
        pcl_acc += closs;
        cw[j] = 0u;                        // positives: con_neg = 0
      } else {
        cw[j] = __float_as_uint(closs);    // uint order == float order (>=0)
      }
    }
    ((uint4*)con)[g] = make_uint4(cw[0], cw[1], cw[2], cw[3]);
  }

  // ---- block reduce pos / loc_loss / sum(closs over positives) ----
  #pragma unroll
  for (int off = 32; off; off >>= 1) {
    loc_acc += __shfl_down(loc_acc, off);
    pcl_acc += __shfl_down(pcl_acc, off);
    pos_acc += __shfl_down(pos_acc, off);
  }
  if (lane == 0) { redf[wid] = loc_acc; redf2[wid] = pcl_acc; redi[wid] = pos_acc; }
  __syncthreads();
  if (tid == 0) {
    float lsum = 0.f, psum = 0.f; int ps = 0;
    for (int w = 0; w < NWAVES; ++w) { lsum += redf[w]; psum += redf2[w]; ps += redi[w]; }
    sh_loc = lsum; sh_pcl = psum; sh_pos = ps;
    sh_prefix = 0u;
    int K = 3*ps; if (K > N_SZ) K = N_SZ;
    sh_rem = K;
  }
  __syncthreads();

  const int pos = sh_pos;
  if (pos > 0) {
    // ---- Phase B: radix select K-th largest of con[] (exact) ----
    for (int shift = 24; shift >= 0; shift -= 8) {
      for (int i = tid; i < NWAVES*256; i += BLOCK) hist[i] = 0u;
      __syncthreads();
      const uint32_t pref  = sh_prefix;
      const uint32_t pmask = (shift == 24) ? 0u : (0xFFFFFFFFu << (shift+8));
      const int rem = sh_rem;
      uint32_t* h = hist + wid*256;
      for (int n = tid; n < N_SZ; n += BLOCK) {
        uint32_t bits = con[n];
        if ((bits & pmask) == pref)
          atomicAdd(&h[(bits >> shift) & 255u], 1u);
      }
      __syncthreads();
      if (tid < 256) {
        uint32_t s = 0;
        #pragma unroll
        for (int w = 0; w < NWAVES; ++w) s += hist[w*256 + tid];
        scan[tid] = s;
      }
      __syncthreads();
      // suffix sum: scan[j] = count of candidates in bins >= j
      for (int d = 1; d < 256; d <<= 1) {
        uint32_t v = 0;
        if (tid < 256 && tid + d < 256) v = scan[tid + d];
        __syncthreads();
        if (tid < 256) scan[tid] += v;
        __syncthreads();
      }
      if (tid < 256) {
        int sj = (int)scan[tid];
        int sn = (tid < 255) ? (int)scan[tid+1] : 0;
        if (sj >= rem && sn < rem) {        // unique j: suffix is monotone
          sh_prefix = pref | ((uint32_t)tid << shift);
          sh_rem = rem - sn;
        }
      }
      __syncthreads();
    }

    // ---- Phase C: sum of selected = sum(v > t) + ties * t ----
    const uint32_t tbits = sh_prefix;
    const int ties = sh_rem;
    float sg = 0.f;
    for (int n = tid; n < N_SZ; n += BLOCK) {
      uint32_t bits = con[n];
      if (bits > tbits) sg += __uint_as_float(bits);
    }
    #pragma unroll
    for (int off = 32; off; off >>= 1) sg += __shfl_down(sg, off);
    if (lane == 0) redf[wid] = sg;
    __syncthreads();
    if (tid == 0) {
      float sum_gt = 0.f;
      for (int w = 0; w < NWAVES; ++w) sum_gt += redf[w];
      float con_loss = sh_pcl + sum_gt + (float)ties * __uint_as_float(tbits);
      float total = sh_loc + con_loss;
      rowout[b] = total / (float)pos;     // num_mask==1, posf==pos
    }
  } else {
    if (tid == 0) rowout[b] = 0.f;        // num_mask==0
  }
}

__global__ void mbl_reduce(const float* __restrict__ rowv, float* __restrict__ out) {
  __shared__ float red[NWAVES];
  const int tid = threadIdx.x;
  float v = (tid < B_SZ) ? rowv[tid] : 0.f;
  #pragma unroll
  for (int off = 32; off; off >>= 1) v += __shfl_down(v, off);
  if ((tid & 63) == 0) red[tid >> 6] = v;
  __syncthreads();
  if (tid == 0) {
    float s = 0.f;
    for (int w = 0; w < NWAVES; ++w) s += red[w];
    out[0] = s / (float)B_SZ;
  }
}

extern "C" void kernel_launch(void* const* d_in, const int* in_sizes, int n_in,
                              void* d_out, int out_size, void* d_ws, size_t ws_size,
                              hipStream_t stream) {
  const float* ploc   = (const float*)d_in[0];
  const float* pconf  = (const float*)d_in[1];
  const float* gloc   = (const float*)d_in[2];
  const int*   glabel = (const int*)  d_in[3];
  const float* dboxes = (const float*)d_in[4];
  float* rowv = (float*)d_ws;   // B_SZ floats of scratch

  hipLaunchKernelGGL(mbl_row_kernel, dim3(B_SZ), dim3(BLOCK), 0, stream,
                     ploc, pconf, gloc, glabel, dboxes, rowv);
  hipLaunchKernelGGL(mbl_reduce, dim3(1), dim3(BLOCK), 0, stream,
                     rowv, (float*)d_out);
}

// Round 6
// 197.525 us; speedup vs baseline: 1.0537x; 1.0537x over previous
//
#include <hip/hip_runtime.h>
#include <cstdint>

#define BLOCK 1024
#define NWAVES (BLOCK/64)   // 16
#define NHIST 8             // histogram copies (waves share pairwise)
#define B_SZ 512
#define N_SZ 8732
#define NG (N_SZ/4)         // 2183

__device__ __forceinline__ float f4c(const float4& v, int j) {
  return j==0 ? v.x : (j==1 ? v.y : (j==2 ? v.z : v.w));
}
__device__ __forceinline__ int i4c(const int4& v, int j) {
  return j==0 ? v.x : (j==1 ? v.y : (j==2 ? v.z : v.w));
}
__device__ __forceinline__ float smoothl1(float d) {
  float ad = fabsf(d);
  return ad < 1.0f ? 0.5f*d*d : ad - 0.5f;
}

// One block per batch row. Phase A: streaming compute of loc/closs/pos,
// con_neg bits -> LDS, fused pass-1 (top byte) histogram. Phase B: radix
// select K-th largest (pass 1 needs no scan; passes 2-4 scan LDS), with a
// single-wave shuffle-based suffix scan (no barrier trees). Phase C: sum of
// selected = sum(v > t) + ties*t.
__global__ __launch_bounds__(BLOCK, 8)
void mbl_row_kernel(const float* __restrict__ ploc,
                    const float* __restrict__ pconf,
                    const float* __restrict__ gloc,
                    const int*   __restrict__ glabel,
                    const float* __restrict__ dboxes,
                    float* __restrict__ rowout)
{
  __shared__ __align__(16) uint32_t con[N_SZ];  // 34928 B
  __shared__ uint32_t hist[NHIST*256];          // 8 KB
  __shared__ float redf[NWAVES], redf2[NWAVES];
  __shared__ int   redi[NWAVES];
  __shared__ int sh_pos, sh_rem;
  __shared__ uint32_t sh_prefix;
  __shared__ float sh_loc, sh_pcl;

  const int b    = blockIdx.x;
  const int tid  = threadIdx.x;
  const int wid  = tid >> 6;
  const int lane = tid & 63;

  const float* pl  = ploc  + (size_t)b * (4*N_SZ);
  const float* pc  = pconf + (size_t)b * (2*N_SZ);
  const float4* gl4  = (const float4*)(gloc   + (size_t)b * (N_SZ*4));
  const int4*   lab4 = (const int4*)  (glabel + (size_t)b * N_SZ);
  const float4* db4  = (const float4*)dboxes;

  // zero pass-1 histogram before phase A (fused hist build)
  for (int i = tid; i < NHIST*256; i += BLOCK) hist[i] = 0u;
  __syncthreads();

  float loc_acc = 0.f, pcl_acc = 0.f;
  int pos_acc = 0;
  uint32_t* hmy = hist + (wid & (NHIST-1))*256;

  // ---- Phase A: streaming compute ----
  for (int g = tid; g < NG; g += BLOCK) {
    const int n = g*4;
    float4 pl0 = *(const float4*)(pl + n);
    float4 pl1 = *(const float4*)(pl + N_SZ   + n);
    float4 pl2 = *(const float4*)(pl + 2*N_SZ + n);
    float4 pl3 = *(const float4*)(pl + 3*N_SZ + n);
    float4 pc0 = *(const float4*)(pc + n);
    float4 pc1 = *(const float4*)(pc + N_SZ + n);
    int4 lb = lab4[g];
    uint32_t cw[4];
    #pragma unroll
    for (int j = 0; j < 4; ++j) {
      float4 g4 = gl4[n + j];
      float4 d4 = db4[n + j];
      float dxy0 = d4.x - 0.5f*d4.z;
      float dxy1 = d4.y - 0.5f*d4.w;
      float dwh0 = d4.x + 0.5f*d4.z;
      float dwh1 = d4.y + 0.5f*d4.w;
      float go0 = __fdividef(g4.x - dxy0, dwh0);
      float go1 = __fdividef(g4.y - dxy1, dwh1);
      float go2 = __logf(__fdividef(g4.z, dwh0));
      float go3 = __logf(__fdividef(g4.w, dwh1));
      float s = smoothl1(f4c(pl0,j) - go0)
              + smoothl1(f4c(pl1,j) - go1)
              + smoothl1(f4c(pl2,j) - go2)
              + smoothl1(f4c(pl3,j) - go3);
      float x0 = f4c(pc0,j), x1 = f4c(pc1,j);
      float d  = x1 - x0;
      float sp = __logf(1.0f + __expf(-fabsf(d)));  // log1p(e^{-|d|})
      int L = i4c(lb, j);
      float closs = sp + (L ? fmaxf(-d, 0.f) : fmaxf(d, 0.f));  // >= 0
      if (L > 0) {
        pos_acc += 1;
        loc_acc += s;
        pcl_acc += closs;
        cw[j] = 0u;
      } else {
        cw[j] = __float_as_uint(closs);    // uint order == float order (>=0)
      }
    }
    ((uint4*)con)[g] = make_uint4(cw[0], cw[1], cw[2], cw[3]);
    atomicAdd(&hmy[cw[0] >> 24], 1u);
    atomicAdd(&hmy[cw[1] >> 24], 1u);
    atomicAdd(&hmy[cw[2] >> 24], 1u);
    atomicAdd(&hmy[cw[3] >> 24], 1u);
  }

  // ---- block reduce pos / loc_loss / sum(closs over positives) ----
  #pragma unroll
  for (int off = 32; off; off >>= 1) {
    loc_acc += __shfl_down(loc_acc, off);
    pcl_acc += __shfl_down(pcl_acc, off);
    pos_acc += __shfl_down(pos_acc, off);
  }
  if (lane == 0) { redf[wid] = loc_acc; redf2[wid] = pcl_acc; redi[wid] = pos_acc; }
  __syncthreads();
  if (tid == 0) {
    float lsum = 0.f, psum = 0.f; int ps = 0;
    for (int w = 0; w < NWAVES; ++w) { lsum += redf[w]; psum += redf2[w]; ps += redi[w]; }
    sh_loc = lsum; sh_pcl = psum; sh_pos = ps;
    sh_prefix = 0u;
    int K = 3*ps; if (K > N_SZ) K = N_SZ;
    sh_rem = K;
  }
  __syncthreads();

  const int pos = sh_pos;
  if (pos > 0) {
    // ---- Phase B: radix select K-th largest of con[] (exact) ----
    for (int shift = 24; shift >= 0; shift -= 8) {
      if (shift != 24) {  // pass-1 hist was built during phase A
        for (int i = tid; i < NHIST*256; i += BLOCK) hist[i] = 0u;
        __syncthreads();
        const uint32_t pref  = sh_prefix;
        const uint32_t pmask = 0xFFFFFFFFu << (shift+8);
        for (int n = tid; n < N_SZ; n += BLOCK) {
          uint32_t bits = con[n];
          if ((bits & pmask) == pref)
            atomicAdd(&hmy[(bits >> shift) & 255u], 1u);
        }
        __syncthreads();
      }
      // single-wave suffix scan + threshold-digit select (lane owns 4 bins)
      if (wid == 0) {
        uint32_t c0 = 0, c1 = 0, c2 = 0, c3 = 0;
        #pragma unroll
        for (int w = 0; w < NHIST; ++w) {
          const uint32_t* h = hist + w*256 + 4*lane;
          c0 += h[0]; c1 += h[1]; c2 += h[2]; c3 += h[3];
        }
        uint32_t sl = c0 + c1 + c2 + c3;
        uint32_t suf = sl;
        #pragma unroll
        for (int off = 1; off < 64; off <<= 1) {
          uint32_t v = __shfl_down(suf, off);
          if (lane + off < 64) suf += v;
        }
        uint32_t ex = suf - sl;        // suffix of bins > 4*lane+3
        uint32_t s3 = ex + c3;
        uint32_t s2 = s3 + c2;
        uint32_t s1 = s2 + c1;
        uint32_t s0 = s1 + c0;
        const uint32_t rem  = (uint32_t)sh_rem;
        const uint32_t pref = sh_prefix;
        if (s0 >= rem && s1 < rem) { sh_prefix = pref | ((uint32_t)(4*lane  ) << shift); sh_rem = (int)(rem - s1); }
        if (s1 >= rem && s2 < rem) { sh_prefix = pref | ((uint32_t)(4*lane+1) << shift); sh_rem = (int)(rem - s2); }
        if (s2 >= rem && s3 < rem) { sh_prefix = pref | ((uint32_t)(4*lane+2) << shift); sh_rem = (int)(rem - s3); }
        if (s3 >= rem && ex < rem) { sh_prefix = pref | ((uint32_t)(4*lane+3) << shift); sh_rem = (int)(rem - ex); }
      }
      __syncthreads();
    }

    // ---- Phase C: sum of selected = sum(v > t) + ties * t ----
    const uint32_t tbits = sh_prefix;
    const int ties = sh_rem;
    float sg = 0.f;
    for (int n = tid; n < N_SZ; n += BLOCK) {
      uint32_t bits = con[n];
      if (bits > tbits) sg += __uint_as_float(bits);
    }
    #pragma unroll
    for (int off = 32; off; off >>= 1) sg += __shfl_down(sg, off);
    if (lane == 0) redf[wid] = sg;
    __syncthreads();
    if (tid == 0) {
      float sum_gt = 0.f;
      for (int w = 0; w < NWAVES; ++w) sum_gt += redf[w];
      float con_loss = sh_pcl + sum_gt + (float)ties * __uint_as_float(tbits);
      float total = sh_loc + con_loss;
      rowout[b] = total / (float)pos;     // num_mask==1, posf==pos
    }
  } else {
    if (tid == 0) rowout[b] = 0.f;        // num_mask==0
  }
}

__global__ void mbl_reduce(const float* __restrict__ rowv, float* __restrict__ out) {
  __shared__ float red[8];
  const int tid = threadIdx.x;
  float v = (tid < B_SZ) ? rowv[tid] : 0.f;
  #pragma unroll
  for (int off = 32; off; off >>= 1) v += __shfl_down(v, off);
  if ((tid & 63) == 0) red[tid >> 6] = v;
  __syncthreads();
  if (tid == 0) {
    float s = 0.f;
    for (int w = 0; w < 8; ++w) s += red[w];
    out[0] = s / (float)B_SZ;
  }
}

extern "C" void kernel_launch(void* const* d_in, const int* in_sizes, int n_in,
                              void* d_out, int out_size, void* d_ws, size_t ws_size,
                              hipStream_t stream) {
  const float* ploc   = (const float*)d_in[0];
  const float* pconf  = (const float*)d_in[1];
  const float* gloc   = (const float*)d_in[2];
  const int*   glabel = (const int*)  d_in[3];
  const float* dboxes = (const float*)d_in[4];
  float* rowv = (float*)d_ws;   // B_SZ floats of scratch

  hipLaunchKernelGGL(mbl_row_kernel, dim3(B_SZ), dim3(BLOCK), 0, stream,
                     ploc, pconf, gloc, glabel, dboxes, rowv);
  hipLaunchKernelGGL(mbl_reduce, dim3(1), dim3(512), 0, stream,
                     rowv, (float*)d_out);
}